// Round 2
// baseline (651.953 us; speedup 1.0000x reference)
//
#include <hip/hip_runtime.h>
#include <type_traits>

#define N_NODES 50000
#define N_EDGES 400000
#define DIM     128
#define HID     60
#define NCLS    40
#define F3      180
#define PADW    192
#define LDSW    200
#define MTILES  3125   // 50000/16
#define WSLOT   (64*192)

typedef __bf16 bf16x8 __attribute__((ext_vector_type(8)));
typedef unsigned short u16x8 __attribute__((ext_vector_type(8)));
typedef float  f32x4  __attribute__((ext_vector_type(4)));
typedef unsigned short u16;
typedef unsigned int   u32;

__device__ __forceinline__ float bf2f(u16 u){ return __uint_as_float(((u32)u)<<16); }
__device__ __forceinline__ u16 f2bf(float f){
  u32 x = __float_as_uint(f);
  x += 0x7fffu + ((x>>16)&1u);   // RNE
  return (u16)(x>>16);
}

__device__ __forceinline__ float ldf(const float* p, int i){ return p[i]; }
__device__ __forceinline__ float ldf(const u16*   p, int i){ return bf2f(p[i]); }

// ---------- graph preprocessing ----------
__global__ void k_hist(const int* __restrict__ ei, int* __restrict__ deg){
  int e = blockIdx.x*blockDim.x + threadIdx.x;
  if (e < N_EDGES) atomicAdd(&deg[ei[N_EDGES + e]], 1);
}

__global__ void k_dis_start(const int* __restrict__ deg, float* __restrict__ dis,
                            int* __restrict__ start, int* __restrict__ gcnt){
  int tid = threadIdx.x;
  int gid = blockIdx.x*256 + tid;
  int d = (gid < N_NODES) ? deg[gid] : 0;
  if (gid < N_NODES) dis[gid] = rsqrtf((float)(d + 1));   // +1 = self loop
  __shared__ int sc[256];
  sc[tid] = d; __syncthreads();
  for (int off = 1; off < 256; off <<= 1){
    int v = 0;
    if (tid >= off) v = sc[tid - off];
    __syncthreads();
    if (tid >= off) sc[tid] += v;
    __syncthreads();
  }
  __shared__ int base;
  if (tid == 255) base = atomicAdd(gcnt, sc[255]);
  __syncthreads();
  if (gid < N_NODES) start[gid] = base + sc[tid] - d;  // exclusive
}

__global__ void k_scatter(const int* __restrict__ ei, const int* __restrict__ start,
                          int* __restrict__ cursor, int* __restrict__ colidx){
  int e = blockIdx.x*blockDim.x + threadIdx.x;
  if (e >= N_EDGES) return;
  int c = ei[N_EDGES + e];
  int p = start[c] + atomicAdd(&cursor[c], 1);
  colidx[p] = ei[e];
}

// ---------- pad all weight matrices (f32 in) to bf16 [64,192], zero-filled ----------
__global__ void k_wpad(const float* __restrict__ w1, const float* __restrict__ w2,
                       const float* __restrict__ w3, const float* __restrict__ wl,
                       u16* __restrict__ wpad){
  int g = blockIdx.x*blockDim.x + threadIdx.x;
  if (g >= 10*WSLOT) return;
  int s = g / WSLOT;
  int idx = g % WSLOT;
  int r = idx / 192, k = idx % 192;
  const float* src; int rows, K;
  if (s < 3)      { src = w1 + s*HID*DIM;      rows = HID;  K = DIM; }
  else if (s < 6) { src = w2 + (s-3)*HID*F3;   rows = HID;  K = F3;  }
  else if (s < 9) { src = w3 + (s-6)*HID*F3;   rows = HID;  K = F3;  }
  else            { src = wl;                  rows = NCLS; K = F3;  }
  u16 v = 0;
  if (r < rows && k < K) v = f2bf(src[r*K + k]);
  wpad[g] = v;
}

// ---------- per-channel epilogue scale/shift: y = gemm*S[c] + T[c] ----------
__global__ void k_prep(const float* __restrict__ g_, const float* __restrict__ b_,
                       const float* __restrict__ m_, const float* __restrict__ v_,
                       const float* __restrict__ bias, float* __restrict__ S,
                       float* __restrict__ T, int mode){
  int c = blockIdx.x*blockDim.x + threadIdx.x;
  if (c >= PADW) return;
  float s = 0.f, t = 0.f;
  if (mode == 0){
    if (c < F3){
      float sv = g_[c] * rsqrtf(v_[c] + 1e-5f);
      s = sv;
      t = bias[c]*sv + b_[c] - m_[c]*sv;  // conv bias folded into BN
    }
  } else {
    if (c < NCLS){ s = 1.f; t = bias[c]; }
  }
  S[c] = s; T[c] = t;
}

// ---------- gather SpMM: hout[i] = dis[i]^2 h[i] + sum_e dis[r]dis[i] h[r] ----------
template<typename TI>
__global__ __launch_bounds__(256) void k_prop(const TI* __restrict__ hin, int lin,
        u16* __restrict__ hout, const float* __restrict__ dis,
        const int* __restrict__ start, const int* __restrict__ deg,
        const int* __restrict__ colidx, int ncols){
  int t = blockIdx.x*blockDim.x + threadIdx.x;
  int node = t >> 6, lane = t & 63;
  if (node >= N_NODES) return;
  float di = dis[node];
  float w = di*di;
  const TI* rp = hin + (size_t)node*lin;
  int c2 = lane + 128;
  bool h2 = c2 < ncols;
  float a0 = w*ldf(rp, lane);
  float a1 = w*ldf(rp, lane + 64);
  float a2 = h2 ? w*ldf(rp, c2) : 0.f;
  int s0 = start[node], e1 = s0 + deg[node];
  for (int e = s0; e < e1; ++e){
    int r = colidx[e];
    float wr = di * dis[r];
    const TI* rr = hin + (size_t)r*lin;
    a0 += wr*ldf(rr, lane);
    a1 += wr*ldf(rr, lane + 64);
    if (h2) a2 += wr*ldf(rr, c2);
  }
  u16* op = hout + (size_t)node*PADW;
  op[lane]      = f2bf(a0);
  op[lane + 64] = f2bf(a1);
  op[c2]        = h2 ? f2bf(a2) : (u16)0;   // zeros pad cols 180..191 (or 128..191)
}

// ---------- MFMA GEMM: out[:,0:ncols] = A[M,K] @ Wp[64,192]^T, epilogue y=acc*S+T ----------
__device__ __forceinline__ bf16x8 lda8(const u16* p){ return *(const bf16x8*)p; }
__device__ __forceinline__ bf16x8 lda8(const float* p){
  f32x4 v0 = ((const f32x4*)p)[0];
  f32x4 v1 = ((const f32x4*)p)[1];
  u16x8 t;
  #pragma unroll
  for (int j = 0; j < 4; ++j){ t[j] = f2bf(v0[j]); t[j+4] = f2bf(v1[j]); }
  return __builtin_bit_cast(bf16x8, t);
}

template<typename TA, typename TO>
__global__ __launch_bounds__(256) void k_gemm(const TA* __restrict__ A, int lda,
        const u16* __restrict__ Wp, TO* __restrict__ out, int ldo,
        const float* __restrict__ S, const float* __restrict__ T,
        int ksteps, int ncols){
  __shared__ u16 Wl[64*LDSW];   // stride 200: row stride 100 dwords -> 2-way (free)
  int tid = threadIdx.x;
  for (int t2 = tid; t2 < 1536; t2 += 256){   // 1536 x 16B chunks
    int r = t2 / 24, c8 = t2 % 24;
    *(u16x8*)(&Wl[r*LDSW + c8*8]) = *(const u16x8*)(Wp + r*192 + c8*8);
  }
  __syncthreads();
  int mt = blockIdx.x*4 + (tid >> 6);
  if (mt >= MTILES) return;
  int lane = tid & 63;
  int rr = lane & 15, kg = lane >> 4;
  const TA* Ap = A + (size_t)(mt*16 + rr)*lda + kg*8;
  f32x4 acc[4] = {{0,0,0,0},{0,0,0,0},{0,0,0,0},{0,0,0,0}};
  for (int ks = 0; ks < ksteps; ++ks){
    bf16x8 a = lda8(Ap + ks*32);
    int kb = ks*32 + kg*8;
    #pragma unroll
    for (int ct = 0; ct < 4; ++ct){
      bf16x8 b = *(const bf16x8*)(&Wl[(ct*16 + rr)*LDSW + kb]);
      acc[ct] = __builtin_amdgcn_mfma_f32_16x16x32_bf16(a, b, acc[ct], 0, 0, 0);
    }
  }
  int orow = mt*16 + kg*4;
  #pragma unroll
  for (int ct = 0; ct < 4; ++ct){
    int col = ct*16 + rr;
    if (col < ncols){
      float sS = S[col], tT = T[col];
      #pragma unroll
      for (int r2 = 0; r2 < 4; ++r2){
        float y = acc[ct][r2]*sS + tT;
        if constexpr (std::is_same<TO,float>::value) out[(size_t)(orow + r2)*ldo + col] = y;
        else out[(size_t)(orow + r2)*ldo + col] = f2bf(y);
      }
    }
  }
}

extern "C" void kernel_launch(void* const* d_in, const int* in_sizes, int n_in,
                              void* d_out, int out_size, void* d_ws, size_t ws_size,
                              hipStream_t stream){
  const float* x    = (const float*)d_in[0];
  const int*   ei   = (const int*)d_in[1];
  const float* w1   = (const float*)d_in[2];
  const float* cb1  = (const float*)d_in[3];
  const float* w2   = (const float*)d_in[4];
  const float* cb2  = (const float*)d_in[5];
  const float* w3   = (const float*)d_in[6];
  const float* cb3  = (const float*)d_in[7];
  const float* bn1g = (const float*)d_in[8],  *bn1b = (const float*)d_in[9];
  const float* bn1m = (const float*)d_in[10], *bn1v = (const float*)d_in[11];
  const float* bn2g = (const float*)d_in[12], *bn2b = (const float*)d_in[13];
  const float* bn2m = (const float*)d_in[14], *bn2v = (const float*)d_in[15];
  const float* bn3g = (const float*)d_in[16], *bn3b = (const float*)d_in[17];
  const float* bn3m = (const float*)d_in[18], *bn3v = (const float*)d_in[19];
  const float* linW = (const float*)d_in[20];
  const float* linb = (const float*)d_in[21];
  float* outp = (float*)d_out;

  char* ws = (char*)d_ws;
  size_t off = 0;
  auto alloc = [&](size_t bytes)->char*{
    char* p = ws + off;
    off = (off + bytes + 255) & ~(size_t)255;
    return p;
  };
  int*   deg    = (int*)alloc((size_t)2*N_NODES*4 + 256); // deg | cursor | gcnt contiguous
  int*   cursor = deg + N_NODES;
  int*   gcnt   = cursor + N_NODES;
  int*   start  = (int*)alloc((size_t)N_NODES*4);
  int*   colidx = (int*)alloc((size_t)N_EDGES*4);
  float* dis    = (float*)alloc((size_t)N_NODES*4);
  float* S      = (float*)alloc(PADW*4);
  float* T      = (float*)alloc(PADW*4);
  u16*   wpad   = (u16*)alloc((size_t)10*WSLOT*2);
  const size_t HB = (size_t)N_NODES*PADW*2;   // 19.2MB per bf16 buffer
  u16* P1 = (u16*)alloc(HB);
  u16* P2 = (u16*)alloc(HB);
  u16* C1 = (u16*)alloc(HB);
  u16* C2 = (u16*)alloc(HB);

  hipMemsetAsync(deg, 0, (size_t)2*N_NODES*4 + 256, stream);
  hipMemsetAsync(C1, 0, 2*HB, stream);   // zeroes pad columns 180..191 of C1/C2

  k_hist<<<(N_EDGES+255)/256, 256, 0, stream>>>(ei, deg);
  k_dis_start<<<(N_NODES+255)/256, 256, 0, stream>>>(deg, dis, start, gcnt);
  k_scatter<<<(N_EDGES+255)/256, 256, 0, stream>>>(ei, start, cursor, colidx);
  k_wpad<<<(10*WSLOT)/256, 256, 0, stream>>>(w1, w2, w3, linW, wpad);

  const int PB = 12500;  // 50000 waves, one per node
  const int GB = (MTILES + 3)/4;

  // ---- layer 1 (input x f32, K=128) ----
  k_prep<<<1, 256, 0, stream>>>(bn1g, bn1b, bn1m, bn1v, cb1, S, T, 0);
  k_prop<float><<<PB, 256, 0, stream>>>(x,  DIM,  P1, dis, start, deg, colidx, DIM);
  k_prop<u16>  <<<PB, 256, 0, stream>>>(P1, PADW, P2, dis, start, deg, colidx, DIM);
  k_gemm<float,u16><<<GB, 256, 0, stream>>>(x,  DIM,  wpad + 0*WSLOT, C1 + 0,   PADW, S + 0,   T + 0,   4, HID);
  k_gemm<u16,u16>  <<<GB, 256, 0, stream>>>(P1, PADW, wpad + 1*WSLOT, C1 + 60,  PADW, S + 60,  T + 60,  4, HID);
  k_gemm<u16,u16>  <<<GB, 256, 0, stream>>>(P2, PADW, wpad + 2*WSLOT, C1 + 120, PADW, S + 120, T + 120, 4, HID);

  // ---- layer 2 (input C1, K=180 -> 192) ----
  k_prep<<<1, 256, 0, stream>>>(bn2g, bn2b, bn2m, bn2v, cb2, S, T, 0);
  k_prop<u16><<<PB, 256, 0, stream>>>(C1, PADW, P1, dis, start, deg, colidx, F3);
  k_prop<u16><<<PB, 256, 0, stream>>>(P1, PADW, P2, dis, start, deg, colidx, F3);
  k_gemm<u16,u16><<<GB, 256, 0, stream>>>(C1, PADW, wpad + 3*WSLOT, C2 + 0,   PADW, S + 0,   T + 0,   6, HID);
  k_gemm<u16,u16><<<GB, 256, 0, stream>>>(P1, PADW, wpad + 4*WSLOT, C2 + 60,  PADW, S + 60,  T + 60,  6, HID);
  k_gemm<u16,u16><<<GB, 256, 0, stream>>>(P2, PADW, wpad + 5*WSLOT, C2 + 120, PADW, S + 120, T + 120, 6, HID);

  // ---- layer 3 (input C2 -> C1) ----
  k_prep<<<1, 256, 0, stream>>>(bn3g, bn3b, bn3m, bn3v, cb3, S, T, 0);
  k_prop<u16><<<PB, 256, 0, stream>>>(C2, PADW, P1, dis, start, deg, colidx, F3);
  k_prop<u16><<<PB, 256, 0, stream>>>(P1, PADW, P2, dis, start, deg, colidx, F3);
  k_gemm<u16,u16><<<GB, 256, 0, stream>>>(C2, PADW, wpad + 6*WSLOT, C1 + 0,   PADW, S + 0,   T + 0,   6, HID);
  k_gemm<u16,u16><<<GB, 256, 0, stream>>>(P1, PADW, wpad + 7*WSLOT, C1 + 60,  PADW, S + 60,  T + 60,  6, HID);
  k_gemm<u16,u16><<<GB, 256, 0, stream>>>(P2, PADW, wpad + 8*WSLOT, C1 + 120, PADW, S + 120, T + 120, 6, HID);

  // ---- final linear (C1 @ linW^T + linb) -> f32 out ----
  k_prep<<<1, 256, 0, stream>>>(linb, linb, linb, linb, linb, S, T, 1);
  k_gemm<u16,float><<<GB, 256, 0, stream>>>(C1, PADW, wpad + 9*WSLOT, outp, NCLS, S, T, 6, NCLS);
}

// Round 3
// 422.209 us; speedup vs baseline: 1.5441x; 1.5441x over previous
//
#include <hip/hip_runtime.h>
#include <type_traits>

#define N_NODES 50000
#define N_EDGES 400000
#define DIM     128
#define HID     60
#define NCLS    40
#define F3      180
#define PADW    192
#define LDSW    200
#define MTILES  3125   // 50000/16
#define WSLOT   (64*192)

typedef __bf16 bf16x8 __attribute__((ext_vector_type(8)));
typedef unsigned short u16x8 __attribute__((ext_vector_type(8)));
typedef float  f32x4  __attribute__((ext_vector_type(4)));
typedef unsigned short u16;
typedef unsigned int   u32;

__device__ __forceinline__ u16 f2bf(float f){
  u32 x = __float_as_uint(f);
  x += 0x7fffu + ((x>>16)&1u);   // RNE
  return (u16)(x>>16);
}
__device__ __forceinline__ float blo(u32 v){ return __uint_as_float(v<<16); }
__device__ __forceinline__ float bhi(u32 v){ return __uint_as_float(v & 0xffff0000u); }

// ---------- graph preprocessing ----------
__global__ void k_hist(const int* __restrict__ ei, int* __restrict__ deg){
  int e = blockIdx.x*blockDim.x + threadIdx.x;
  if (e < N_EDGES) atomicAdd(&deg[ei[N_EDGES + e]], 1);
}

__global__ void k_dis_start(const int* __restrict__ deg, float* __restrict__ dis,
                            int* __restrict__ start, int* __restrict__ gcnt){
  int tid = threadIdx.x;
  int gid = blockIdx.x*256 + tid;
  int d = (gid < N_NODES) ? deg[gid] : 0;
  if (gid < N_NODES) dis[gid] = rsqrtf((float)(d + 1));   // +1 = self loop
  __shared__ int sc[256];
  sc[tid] = d; __syncthreads();
  for (int off = 1; off < 256; off <<= 1){
    int v = 0;
    if (tid >= off) v = sc[tid - off];
    __syncthreads();
    if (tid >= off) sc[tid] += v;
    __syncthreads();
  }
  __shared__ int base;
  if (tid == 255) base = atomicAdd(gcnt, sc[255]);
  __syncthreads();
  if (gid < N_NODES) start[gid] = base + sc[tid] - d;  // exclusive
}

// edge record: {neighbor row index, bits of dis[row]}
__global__ void k_scatter(const int* __restrict__ ei, const int* __restrict__ start,
                          int* __restrict__ cursor, const float* __restrict__ dis,
                          int2* __restrict__ nbr){
  int e = blockIdx.x*blockDim.x + threadIdx.x;
  if (e >= N_EDGES) return;
  int r = ei[e];
  int c = ei[N_EDGES + e];
  int p = start[c] + atomicAdd(&cursor[c], 1);
  nbr[p] = make_int2(r, __float_as_int(dis[r]));
}

// ---------- x (f32) -> padded bf16 [N,192], only cols 0..127 written ----------
__global__ void k_x0(const float* __restrict__ x, u16* __restrict__ X0){
  int t = blockIdx.x*256 + threadIdx.x;
  if (t >= N_NODES*32) return;
  int node = t >> 5, j = (t & 31)*4;
  f32x4 v = *(const f32x4*)(x + (size_t)node*DIM + j);
  uint2 o;
  o.x = (u32)f2bf(v[0]) | ((u32)f2bf(v[1])<<16);
  o.y = (u32)f2bf(v[2]) | ((u32)f2bf(v[3])<<16);
  *(uint2*)(X0 + (size_t)node*PADW + j) = o;
}

// ---------- pad all weight matrices (f32 in) to bf16 [64,192], zero-filled ----------
__global__ void k_wpad(const float* __restrict__ w1, const float* __restrict__ w2,
                       const float* __restrict__ w3, const float* __restrict__ wl,
                       u16* __restrict__ wpad){
  int g = blockIdx.x*blockDim.x + threadIdx.x;
  if (g >= 10*WSLOT) return;
  int s = g / WSLOT;
  int idx = g % WSLOT;
  int r = idx / 192, k = idx % 192;
  const float* src; int rows, K;
  if (s < 3)      { src = w1 + s*HID*DIM;      rows = HID;  K = DIM; }
  else if (s < 6) { src = w2 + (s-3)*HID*F3;   rows = HID;  K = F3;  }
  else if (s < 9) { src = w3 + (s-6)*HID*F3;   rows = HID;  K = F3;  }
  else            { src = wl;                  rows = NCLS; K = F3;  }
  u16 v = 0;
  if (r < rows && k < K) v = f2bf(src[r*K + k]);
  wpad[g] = v;
}

// ---------- all epilogue scale/shift sets in one dispatch ----------
struct PrepPtrs {
  const float *g0,*b0,*m0,*v0,*cb0;
  const float *g1,*b1,*m1,*v1,*cb1;
  const float *g2,*b2,*m2,*v2,*cb2;
  const float *linb;
};
__global__ void k_prep(PrepPtrs pp, float* __restrict__ S, float* __restrict__ T){
  int b = blockIdx.x, c = threadIdx.x;
  if (c >= PADW) return;
  float s = 0.f, t = 0.f;
  if (b < 3){
    const float* g  = b==0?pp.g0 :b==1?pp.g1 :pp.g2;
    const float* bb = b==0?pp.b0 :b==1?pp.b1 :pp.b2;
    const float* m  = b==0?pp.m0 :b==1?pp.m1 :pp.m2;
    const float* v  = b==0?pp.v0 :b==1?pp.v1 :pp.v2;
    const float* cb = b==0?pp.cb0:b==1?pp.cb1:pp.cb2;
    if (c < F3){
      float sv = g[c] * rsqrtf(v[c] + 1e-5f);
      s = sv;
      t = cb[c]*sv + bb[c] - m[c]*sv;   // conv bias folded into BN
    }
  } else if (c < NCLS){ s = 1.f; t = pp.linb[c]; }
  S[b*PADW + c] = s; T[b*PADW + c] = t;
}

// ---------- gather SpMM: hout[i] = dis[i]^2 h[i] + sum_e (di*dis[r]) h[r] ----------
// one wave per node; lane < nlanes handles cols [4*lane .. 4*lane+3] (uint2 = 4 bf16)
__global__ __launch_bounds__(256) void k_prop(const u16* __restrict__ hin,
        u16* __restrict__ hout, const float* __restrict__ dis,
        const int* __restrict__ start, const int* __restrict__ deg,
        const int2* __restrict__ nbr, int nlanes){
  int t = blockIdx.x*256 + threadIdx.x;
  int node = t >> 6, lane = t & 63;
  if (node >= N_NODES || lane >= nlanes) return;
  float di = dis[node];
  const uint2* rp = (const uint2*)(hin + (size_t)node*PADW);
  uint2 sv = rp[lane];
  float w = di*di;
  float ax = w*blo(sv.x), ay = w*bhi(sv.x), az = w*blo(sv.y), aw = w*bhi(sv.y);
  int cnt = deg[node];
  const int2* nb = nbr + start[node];
  int2 Z = make_int2(node, 0);   // clamp: valid row, zero weight
  for (int e = 0; e < cnt; e += 4){
    int2 m0 = nb[e];
    int2 m1 = (e+1 < cnt) ? nb[e+1] : Z;
    int2 m2 = (e+2 < cnt) ? nb[e+2] : Z;
    int2 m3 = (e+3 < cnt) ? nb[e+3] : Z;
    const uint2* q0 = (const uint2*)(hin + (size_t)m0.x*PADW);
    const uint2* q1 = (const uint2*)(hin + (size_t)m1.x*PADW);
    const uint2* q2 = (const uint2*)(hin + (size_t)m2.x*PADW);
    const uint2* q3 = (const uint2*)(hin + (size_t)m3.x*PADW);
    uint2 v0 = q0[lane], v1 = q1[lane], v2 = q2[lane], v3 = q3[lane];
    float w0 = di*__int_as_float(m0.y), w1 = di*__int_as_float(m1.y);
    float w2 = di*__int_as_float(m2.y), w3 = di*__int_as_float(m3.y);
    ax = fmaf(w0, blo(v0.x), ax); ay = fmaf(w0, bhi(v0.x), ay);
    az = fmaf(w0, blo(v0.y), az); aw = fmaf(w0, bhi(v0.y), aw);
    ax = fmaf(w1, blo(v1.x), ax); ay = fmaf(w1, bhi(v1.x), ay);
    az = fmaf(w1, blo(v1.y), az); aw = fmaf(w1, bhi(v1.y), aw);
    ax = fmaf(w2, blo(v2.x), ax); ay = fmaf(w2, bhi(v2.x), ay);
    az = fmaf(w2, blo(v2.y), az); aw = fmaf(w2, bhi(v2.y), aw);
    ax = fmaf(w3, blo(v3.x), ax); ay = fmaf(w3, bhi(v3.x), ay);
    az = fmaf(w3, blo(v3.y), az); aw = fmaf(w3, bhi(v3.y), aw);
  }
  uint2 o;
  o.x = (u32)f2bf(ax) | ((u32)f2bf(ay)<<16);
  o.y = (u32)f2bf(az) | ((u32)f2bf(aw)<<16);
  ((uint2*)(hout + (size_t)node*PADW))[lane] = o;
}

// ---------- MFMA GEMM core (A bf16 [M,PADW], W slot in LDS) ----------
template<typename TO>
__device__ __forceinline__ void gemm_core(const u16* __restrict__ A,
        const u16* __restrict__ Wp, TO* __restrict__ out, int ldo,
        const float* __restrict__ S, const float* __restrict__ T,
        int ksteps, int ncols, u16* Wl){
  int tid = threadIdx.x;
  for (int t2 = tid; t2 < 1536; t2 += 256){   // 1536 x 16B chunks
    int r = t2 / 24, c8 = t2 % 24;
    *(u16x8*)(&Wl[r*LDSW + c8*8]) = *(const u16x8*)(Wp + r*192 + c8*8);
  }
  __syncthreads();
  int mt = blockIdx.x*4 + (tid >> 6);
  if (mt >= MTILES) return;
  int lane = tid & 63;
  int rr = lane & 15, kg = lane >> 4;
  const u16* Ap = A + (size_t)(mt*16 + rr)*PADW + kg*8;
  f32x4 acc[4] = {{0,0,0,0},{0,0,0,0},{0,0,0,0},{0,0,0,0}};
  for (int ks = 0; ks < ksteps; ++ks){
    bf16x8 a = *(const bf16x8*)(Ap + ks*32);
    int kb = ks*32 + kg*8;
    #pragma unroll
    for (int ct = 0; ct < 4; ++ct){
      bf16x8 b = *(const bf16x8*)(&Wl[(ct*16 + rr)*LDSW + kb]);
      acc[ct] = __builtin_amdgcn_mfma_f32_16x16x32_bf16(a, b, acc[ct], 0, 0, 0);
    }
  }
  int orow = mt*16 + kg*4;
  #pragma unroll
  for (int ct = 0; ct < 4; ++ct){
    int col = ct*16 + rr;
    if (col < ncols){
      float sS = S[col], tT = T[col];
      #pragma unroll
      for (int r2 = 0; r2 < 4; ++r2){
        float y = acc[ct][r2]*sS + tT;
        if constexpr (std::is_same<TO,float>::value) out[(size_t)(orow + r2)*ldo + col] = y;
        else out[(size_t)(orow + r2)*ldo + col] = f2bf(y);
      }
    }
  }
}

// 3 powers in one dispatch: blockIdx.y = p
__global__ __launch_bounds__(256) void k_gemm3(const u16* __restrict__ A0,
        const u16* __restrict__ A1, const u16* __restrict__ A2,
        const u16* __restrict__ Wbase, u16* __restrict__ outb,
        const float* __restrict__ Sb, const float* __restrict__ Tb, int ksteps){
  __shared__ u16 Wl[64*LDSW];
  int p = blockIdx.y;
  const u16* A = (p==0) ? A0 : (p==1) ? A1 : A2;
  gemm_core<u16>(A, Wbase + p*WSLOT, outb + p*HID, PADW, Sb + p*HID, Tb + p*HID,
                 ksteps, HID, Wl);
}

__global__ __launch_bounds__(256) void k_gemmf(const u16* __restrict__ A,
        const u16* __restrict__ Wp, float* __restrict__ out,
        const float* __restrict__ S, const float* __restrict__ T){
  __shared__ u16 Wl[64*LDSW];
  gemm_core<float>(A, Wp, out, NCLS, S, T, 6, NCLS, Wl);
}

extern "C" void kernel_launch(void* const* d_in, const int* in_sizes, int n_in,
                              void* d_out, int out_size, void* d_ws, size_t ws_size,
                              hipStream_t stream){
  const float* x    = (const float*)d_in[0];
  const int*   ei   = (const int*)d_in[1];
  const float* w1   = (const float*)d_in[2];
  const float* cb1  = (const float*)d_in[3];
  const float* w2   = (const float*)d_in[4];
  const float* cb2  = (const float*)d_in[5];
  const float* w3   = (const float*)d_in[6];
  const float* cb3  = (const float*)d_in[7];
  const float* bn1g = (const float*)d_in[8],  *bn1b = (const float*)d_in[9];
  const float* bn1m = (const float*)d_in[10], *bn1v = (const float*)d_in[11];
  const float* bn2g = (const float*)d_in[12], *bn2b = (const float*)d_in[13];
  const float* bn2m = (const float*)d_in[14], *bn2v = (const float*)d_in[15];
  const float* bn3g = (const float*)d_in[16], *bn3b = (const float*)d_in[17];
  const float* bn3m = (const float*)d_in[18], *bn3v = (const float*)d_in[19];
  const float* linW = (const float*)d_in[20];
  const float* linb = (const float*)d_in[21];
  float* outp = (float*)d_out;

  char* ws = (char*)d_ws;
  size_t off = 0;
  auto alloc = [&](size_t bytes)->char*{
    char* p = ws + off;
    off = (off + bytes + 255) & ~(size_t)255;
    return p;
  };
  int*   deg    = (int*)alloc((size_t)2*N_NODES*4 + 256); // deg | cursor | gcnt
  int*   cursor = deg + N_NODES;
  int*   gcnt   = cursor + N_NODES;
  int*   start  = (int*)alloc((size_t)N_NODES*4);
  int2*  nbr    = (int2*)alloc((size_t)N_EDGES*8);
  float* dis    = (float*)alloc((size_t)N_NODES*4);
  float* S      = (float*)alloc(4*PADW*4);
  float* T      = (float*)alloc(4*PADW*4);
  u16*   wpad   = (u16*)alloc((size_t)10*WSLOT*2);
  const size_t HB = (size_t)N_NODES*PADW*2;   // 19.2MB per bf16 buffer
  u16* P1 = (u16*)alloc(HB);
  u16* P2 = (u16*)alloc(HB);
  u16* C1 = (u16*)alloc(HB);
  u16* C2 = (u16*)alloc(HB);   // doubles as X0: X0's last read precedes C2's first write
  u16* X0 = C2;

  hipMemsetAsync(deg, 0, (size_t)2*N_NODES*4 + 256, stream);

  k_hist<<<(N_EDGES+255)/256, 256, 0, stream>>>(ei, deg);
  k_dis_start<<<(N_NODES+255)/256, 256, 0, stream>>>(deg, dis, start, gcnt);
  k_scatter<<<(N_EDGES+255)/256, 256, 0, stream>>>(ei, start, cursor, dis, nbr);
  k_wpad<<<(10*WSLOT)/256, 256, 0, stream>>>(w1, w2, w3, linW, wpad);
  k_x0<<<(N_NODES*32+255)/256, 256, 0, stream>>>(x, X0);
  PrepPtrs pp{bn1g,bn1b,bn1m,bn1v,cb1, bn2g,bn2b,bn2m,bn2v,cb2,
              bn3g,bn3b,bn3m,bn3v,cb3, linb};
  k_prep<<<4, PADW, 0, stream>>>(pp, S, T);

  const int PB = 12500;           // one wave per node
  const dim3 G3((MTILES + 3)/4, 3);

  // ---- layer 1 (A = X0, K=128 -> ksteps 4) ----
  k_prop<<<PB, 256, 0, stream>>>(X0, P1, dis, start, deg, nbr, 32);
  k_prop<<<PB, 256, 0, stream>>>(P1, P2, dis, start, deg, nbr, 32);
  k_gemm3<<<G3, 256, 0, stream>>>(X0, P1, P2, wpad + 0*WSLOT, C1, S + 0*PADW, T + 0*PADW, 4);

  // ---- layer 2 (A = C1, K=180 -> ksteps 6; pad cols killed by zero W rows) ----
  k_prop<<<PB, 256, 0, stream>>>(C1, P1, dis, start, deg, nbr, 48);
  k_prop<<<PB, 256, 0, stream>>>(P1, P2, dis, start, deg, nbr, 48);
  k_gemm3<<<G3, 256, 0, stream>>>(C1, P1, P2, wpad + 3*WSLOT, C2, S + 1*PADW, T + 1*PADW, 6);

  // ---- layer 3 (A = C2 -> C1) ----
  k_prop<<<PB, 256, 0, stream>>>(C2, P1, dis, start, deg, nbr, 48);
  k_prop<<<PB, 256, 0, stream>>>(P1, P2, dis, start, deg, nbr, 48);
  k_gemm3<<<G3, 256, 0, stream>>>(C2, P1, P2, wpad + 6*WSLOT, C1, S + 2*PADW, T + 2*PADW, 6);

  // ---- final linear (C1 @ linW^T + linb) -> f32 out ----
  k_gemmf<<<(MTILES + 3)/4, 256, 0, stream>>>(C1, wpad + 9*WSLOT, outp, S + 3*PADW, T + 3*PADW);
}